// Round 11
// baseline (565.940 us; speedup 1.0000x reference)
//
#include <hip/hip_runtime.h>

#define Bc 2
#define Sc 2048
#define Hc 2048
#define NHc 16
#define HDc 128
#define SLOTSc 16
#define NROWS (Bc * Sc)     // 4096
#define NU (NROWS * 4)      // 16384 units: (row, quarter); quarter = 4 heads
#define GRIDB 768           // blocks; multiple of 4 so quarter (and head) is fixed per block

typedef float v2f __attribute__((ext_vector_type(2)));

// Chain for one unit: new_mask, new_stack (in place on sv), gate reduce-scatter,
// distributed masked softmax, bpermute broadcast, weighted sum, residual, store.
// sv passed by reference-to-array: each call site binds a DISTINCT static array.
__device__ __forceinline__ void unit_chain(
    v2f (&sv)[SLOTSc], const float a_push, const float a_pop, const float a_stay,
    float m_d, const v2f kv, const v2f wg, const float bg, const float rw,
    const int row, const int n, const int lane, const int cls, const int grp,
    float* __restrict__ out, float* __restrict__ new_stack,
    float* __restrict__ new_mask)
{
    // distributed new_mask (2 bpermute)
    {
        int ap_prev = (grp | (cls == 0 ? 0 : cls - 1)) << 2;
        int ap_next = (grp | (cls == 15 ? 15 : cls + 1)) << 2;
        float m_prev = __int_as_float(__builtin_amdgcn_ds_bpermute(ap_prev, __float_as_int(m_d)));
        float m_next = __int_as_float(__builtin_amdgcn_ds_bpermute(ap_next, __float_as_int(m_d)));
        m_prev = (cls == 0)  ? 1.f : m_prev;
        m_next = (cls == 15) ? 0.f : m_next;
        m_d = a_push * m_prev + a_pop * m_next + a_stay * m_d;
    }
    if (lane < SLOTSc)
        new_mask[((size_t)row * NHc + n) * SLOTSc + lane] = m_d;

    const size_t sbase = ((size_t)row * NHc + n) * (size_t)(SLOTSc * HDc);
    v2f* nst2 = (v2f*)(new_stack + sbase);
    float p[SLOTSc];
    {
        v2f prev = kv;
        #pragma unroll
        for (int k = 0; k < SLOTSc; ++k) {
            v2f cur = sv[k];
            v2f nxt;
            if (k < SLOTSc - 1) nxt = sv[k + 1];
            else { nxt.x = 0.f; nxt.y = 0.f; }
            v2f ns;
            ns.x = a_push * prev.x + a_pop * nxt.x + a_stay * cur.x;
            ns.y = a_push * prev.y + a_pop * nxt.y + a_stay * cur.y;
            sv[k] = ns;
            nst2[k * 64 + lane] = ns;
            p[k] = ns.x * wg.x + ns.y * wg.y;
            prev = cur;
        }
    }

    // merge-butterfly reduce-scatter (slot k -> lanes lane&15==k)
    float w8[8];
    #pragma unroll
    for (int j = 0; j < 8; ++j) {
        float a = p[2 * j], b = p[2 * j + 1];
        bool hi = (lane & 1);
        float keep = hi ? b : a;
        float send = hi ? a : b;
        w8[j] = keep + __shfl_xor(send, 1, 64);
    }
    float w4[4];
    #pragma unroll
    for (int j = 0; j < 4; ++j) {
        float a = w8[2 * j], b = w8[2 * j + 1];
        bool hi = (lane & 2);
        float keep = hi ? b : a;
        float send = hi ? a : b;
        w4[j] = keep + __shfl_xor(send, 2, 64);
    }
    float w2[2];
    #pragma unroll
    for (int j = 0; j < 2; ++j) {
        float a = w4[2 * j], b = w4[2 * j + 1];
        bool hi = (lane & 4);
        float keep = hi ? b : a;
        float send = hi ? a : b;
        w2[j] = keep + __shfl_xor(send, 4, 64);
    }
    float u;
    {
        float a = w2[0], b = w2[1];
        bool hi = (lane & 8);
        float keep = hi ? b : a;
        float send = hi ? a : b;
        u = keep + __shfl_xor(send, 8, 64);
    }
    u += __shfl_xor(u, 16, 64);
    u += __shfl_xor(u, 32, 64);

    // distributed masked softmax over 16 slots
    float g = u + bg + (1.f - m_d) * -1000000000.0f;
    float mx = g;
    mx = fmaxf(mx, __shfl_xor(mx, 1, 64));
    mx = fmaxf(mx, __shfl_xor(mx, 2, 64));
    mx = fmaxf(mx, __shfl_xor(mx, 4, 64));
    mx = fmaxf(mx, __shfl_xor(mx, 8, 64));
    float e = __expf(g - mx);
    float ssum = e;
    ssum += __shfl_xor(ssum, 1, 64);
    ssum += __shfl_xor(ssum, 2, 64);
    ssum += __shfl_xor(ssum, 4, 64);
    ssum += __shfl_xor(ssum, 8, 64);
    float gw_d = e / ssum;

    // broadcast gate weights; weighted sum + residual
    v2f mo; mo.x = 0.f; mo.y = 0.f;
    const int grpb = grp << 2;
    #pragma unroll
    for (int k = 0; k < SLOTSc; ++k) {
        float gwk = __int_as_float(
            __builtin_amdgcn_ds_bpermute(grpb | (k << 2), __float_as_int(gw_d)));
        mo.x = fmaf(gwk, sv[k].x, mo.x);
        mo.y = fmaf(gwk, sv[k].y, mo.y);
    }
    v2f ov;
    ov.x = mo.x * rw + kv.x;
    ov.y = mo.y * rw + kv.y;
    *(v2f*)(out + (size_t)row * Hc + n * HDc + 2 * lane) = ov;
}

// ---------------------------------------------------------------------------
// Persistent pipelined kernel. 768 blocks x 256 thr (4 waves = 4 heads of one
// quarter). Block b grid-strides units u = b, b+768, ... (768 % 4 == 0 so the
// quarter — hence each wave's head and W rows — is FIXED per block).
// 2-deep pipeline: while chaining unit i (svA/svB), unit i+768's hidden stage
// + sv burst + mask are already in flight -> HBM read issue never idles.
// Double-buffered 8 KB LDS hid. launch_bounds(256,3): VGPR cap ~170 for
// svA+svB (64) + pipeline state; 3 blocks/CU resident.
// ---------------------------------------------------------------------------
__global__ __launch_bounds__(256, 3) void stack_persist(
    const float* __restrict__ hidden,     // [4096][2048]
    const float* __restrict__ stack,      // [4096][16][16][128]
    const float* __restrict__ mask,       // [4096][16][16]
    const float* __restrict__ W_action,   // [48][2048]
    const float* __restrict__ b_action,   // [48]
    const float* __restrict__ W_gate,     // [128]
    const float* __restrict__ b_gate,     // [1]
    const float* __restrict__ res_weight, // [1]
    float* __restrict__ out,              // [4096][2048]
    float* __restrict__ new_stack,        // [4096][16][16][128]
    float* __restrict__ new_mask)         // [4096][16][16]
{
    __shared__ float hid[2][Hc]; // 16 KB

    const int tid  = threadIdx.x;
    const int lane = tid & 63;
    const int wave = tid >> 6;          // 0..3
    const int q    = blockIdx.x & 3;    // fixed for this block
    const int n    = q * 4 + wave;      // this wave's head, fixed
    const int cls  = lane & 15;
    const int grp  = lane & 48;

    // loop-invariant operands
    v2f wg = *(const v2f*)(W_gate + 2 * lane);
    const float bg  = b_gate[0];
    const float rw  = res_weight[0];
    const float ba0 = b_action[3 * n + 0];
    const float ba1 = b_action[3 * n + 1];
    const float ba2 = b_action[3 * n + 2];
    const float4* W0 = (const float4*)(W_action + (size_t)(3 * n) * Hc);
    const float4* W1 = W0 + (Hc / 4);
    const float4* W2 = W1 + (Hc / 4);

    v2f svA[SLOTSc], svB[SLOTSc];
    float m_cur, m_nxt;

    // ---------------- prologue: unit u0 = blockIdx.x ----------------
    int u = blockIdx.x;
    {
        const int row = u >> 2;
        const float4* hr = (const float4*)(hidden + (size_t)row * Hc);
        float4 h0 = hr[tid];
        float4 h1 = hr[256 + tid];
        const size_t sb = ((size_t)row * NHc + n) * (size_t)(SLOTSc * HDc);
        const v2f* st2 = (const v2f*)(stack + sb);
        #pragma unroll
        for (int k = 0; k < SLOTSc; ++k) svA[k] = st2[k * 64 + lane];
        m_cur = mask[((size_t)row * NHc + n) * SLOTSc + cls];
        ((float4*)hid[0])[tid] = h0;
        ((float4*)hid[0])[256 + tid] = h1;
    }
    __syncthreads();

    int cur = 0;
    bool phase = true; // true: current unit's sv in svA
    const float scale = 0.08838834764831845f; // 1/sqrt(128)

    while (true) {
        const int row  = u >> 2;
        const int un   = u + GRIDB;
        const bool pref = (un < NU);   // block-uniform

        // ---- GEMV for this unit from hid[cur] (W from L2; no HBM ahead) ----
        float s0 = 0.f, s1 = 0.f, s2 = 0.f;
        {
            const float4* hl4 = (const float4*)hid[cur];
            #pragma unroll 2
            for (int j = 0; j < 8; ++j) {
                float4 a  = hl4[lane + j * 64];
                float4 b0 = W0[lane + j * 64];
                float4 b1 = W1[lane + j * 64];
                float4 b2 = W2[lane + j * 64];
                s0 = fmaf(a.x, b0.x, fmaf(a.y, b0.y, fmaf(a.z, b0.z, fmaf(a.w, b0.w, s0))));
                s1 = fmaf(a.x, b1.x, fmaf(a.y, b1.y, fmaf(a.z, b1.z, fmaf(a.w, b1.w, s1))));
                s2 = fmaf(a.x, b2.x, fmaf(a.y, b2.y, fmaf(a.z, b2.z, fmaf(a.w, b2.w, s2))));
            }
        }
        #pragma unroll
        for (int o = 32; o; o >>= 1) {
            s0 += __shfl_xor(s0, o, 64);
            s1 += __shfl_xor(s1, o, 64);
            s2 += __shfl_xor(s2, o, 64);
        }
        float l0 = (s0 + ba0) * scale;
        float l1 = (s1 + ba1) * scale;
        float l2 = (s2 + ba2) * scale;
        float lm = fmaxf(l0, fmaxf(l1, l2));
        float e0 = __expf(l0 - lm), e1 = __expf(l1 - lm), e2 = __expf(l2 - lm);
        float inv3 = 1.f / (e0 + e1 + e2);
        const float a_push = e0 * inv3;
        const float a_pop  = e1 * inv3;
        const float a_stay = e2 * inv3;

        v2f kv = *(const v2f*)(&hid[cur][n * HDc + 2 * lane]);

        // ---- prefetch next unit (issued AFTER W loads; hides under chain) ----
        float4 h0n, h1n;
        if (pref) {
            const int rown = un >> 2;
            const float4* hr = (const float4*)(hidden + (size_t)rown * Hc);
            h0n = hr[tid];
            h1n = hr[256 + tid];
            const size_t sbn = ((size_t)rown * NHc + n) * (size_t)(SLOTSc * HDc);
            const v2f* stn = (const v2f*)(stack + sbn);
            if (phase) {
                #pragma unroll
                for (int k = 0; k < SLOTSc; ++k) svB[k] = stn[k * 64 + lane];
            } else {
                #pragma unroll
                for (int k = 0; k < SLOTSc; ++k) svA[k] = stn[k * 64 + lane];
            }
            m_nxt = mask[((size_t)rown * NHc + n) * SLOTSc + cls];
        }

        // ---- chain on current sv (oldest in vmcnt queue: no prefetch drain) ----
        if (phase)
            unit_chain(svA, a_push, a_pop, a_stay, m_cur, kv, wg, bg, rw,
                       row, n, lane, cls, grp, out, new_stack, new_mask);
        else
            unit_chain(svB, a_push, a_pop, a_stay, m_cur, kv, wg, bg, rw,
                       row, n, lane, cls, grp, out, new_stack, new_mask);

        if (!pref) break;

        // ---- finish staging next row; swap buffers ----
        ((float4*)hid[cur ^ 1])[tid] = h0n;
        ((float4*)hid[cur ^ 1])[256 + tid] = h1n;
        __syncthreads();
        cur ^= 1;
        phase = !phase;
        m_cur = m_nxt;
        u = un;
    }
}

extern "C" void kernel_launch(void* const* d_in, const int* in_sizes, int n_in,
                              void* d_out, int out_size, void* d_ws, size_t ws_size,
                              hipStream_t stream) {
    const float* hidden     = (const float*)d_in[0];
    const float* stack      = (const float*)d_in[1];
    const float* mask       = (const float*)d_in[2];
    const float* W_action   = (const float*)d_in[3];
    const float* b_action   = (const float*)d_in[4];
    const float* W_gate     = (const float*)d_in[5];
    const float* b_gate     = (const float*)d_in[6];
    const float* res_weight = (const float*)d_in[7];

    float* out       = (float*)d_out;
    float* new_stack = out + (size_t)Bc * Sc * Hc;
    float* new_mask  = new_stack + (size_t)Bc * Sc * NHc * SLOTSc * HDc;

    hipLaunchKernelGGL(stack_persist, dim3(GRIDB), dim3(256), 0, stream,
                       hidden, stack, mask, W_action, b_action,
                       W_gate, b_gate, res_weight,
                       out, new_stack, new_mask);
}

// Round 12
// 253.610 us; speedup vs baseline: 2.2315x; 2.2315x over previous
//
#include <hip/hip_runtime.h>

#define Bc 2
#define Sc 2048
#define Hc 2048
#define NHc 16
#define HDc 128
#define SLOTSc 16
#define NROWS (Bc * Sc)   // 4096

typedef float v2f __attribute__((ext_vector_type(2)));

// ---------------------------------------------------------------------------
// R12: one block = one (b,s) row, BOTH halves pipelined.
// Block = 512 thr = 8 waves. Wave w handles head n0 = w (half 0) then
// n1 = 8 + w (half 1). Lane l owns dims 2l,2l+1 (8B/lane coalesced).
//
// Timeline per block (in-order vmcnt queue discipline):
//   stage hid (8 KB) + issue svA burst (half0) + m0  -> barrier (drains all)
//   GEMV0 (W L2-resident)                                [reads: L2]
//   issue svB burst (half1) + m1                         [HBM, flies under...]
//   reduce+softmax0, chain0 on svA                       [~2000 cy cover]
//   GEMV1 (W-wait drains svB - landed by now)
//   reduce+softmax1, chain1 on svB
// Register diet: p[] folded pairwise into the merge tree (live 16 -> 2);
// everything static-indexed, manually duplicated (no helper-by-reference —
// R11's spill lesson). Peak ~115 VGPR < 128 cap at launch_bounds(512,4).
// ---------------------------------------------------------------------------
__global__ __launch_bounds__(512, 4) void stack_fused2(
    const float* __restrict__ hidden,     // [4096][2048]
    const float* __restrict__ stack,      // [4096][16][16][128]
    const float* __restrict__ mask,       // [4096][16][16]
    const float* __restrict__ W_action,   // [48][2048]
    const float* __restrict__ b_action,   // [48]
    const float* __restrict__ W_gate,     // [128]
    const float* __restrict__ b_gate,     // [1]
    const float* __restrict__ res_weight, // [1]
    float* __restrict__ out,              // [4096][2048]
    float* __restrict__ new_stack,        // [4096][16][16][128]
    float* __restrict__ new_mask)         // [4096][16][16]
{
    __shared__ float hid[Hc]; // 8 KB

    const int row  = blockIdx.x;
    const int tid  = threadIdx.x;
    const int lane = tid & 63;
    const int wave = tid >> 6;
    const int n0   = wave;
    const int n1   = 8 + wave;
    const int cls  = lane & 15;
    const int grp  = lane & 48;
    const float scale = 0.08838834764831845f; // 1/sqrt(128)

    // ---- stage hidden row + issue svA burst (half 0) ----
    ((float4*)hid)[tid] = ((const float4*)(hidden + (size_t)row * Hc))[tid];

    const size_t sbase0 = ((size_t)row * NHc + n0) * (size_t)(SLOTSc * HDc);
    const v2f* stA = (const v2f*)(stack + sbase0);
    v2f svA[SLOTSc];
    #pragma unroll
    for (int k = 0; k < SLOTSc; ++k) svA[k] = stA[k * 64 + lane];
    float m0 = mask[((size_t)row * NHc + n0) * SLOTSc + cls];

    v2f wg = *(const v2f*)(W_gate + 2 * lane);
    const float bg = b_gate[0];
    const float rw = res_weight[0];

    __syncthreads();

    // ================= half 0: GEMV =================
    float s0 = 0.f, s1 = 0.f, s2 = 0.f;
    {
        const float4* hl4 = (const float4*)hid;
        const float4* W0 = (const float4*)(W_action + (size_t)(3 * n0) * Hc);
        const float4* W1 = W0 + (Hc / 4);
        const float4* W2 = W1 + (Hc / 4);
        #pragma unroll 2
        for (int j = 0; j < 8; ++j) {
            float4 a  = hl4[lane + j * 64];
            float4 b0 = W0[lane + j * 64];
            float4 b1 = W1[lane + j * 64];
            float4 b2 = W2[lane + j * 64];
            s0 = fmaf(a.x, b0.x, fmaf(a.y, b0.y, fmaf(a.z, b0.z, fmaf(a.w, b0.w, s0))));
            s1 = fmaf(a.x, b1.x, fmaf(a.y, b1.y, fmaf(a.z, b1.z, fmaf(a.w, b1.w, s1))));
            s2 = fmaf(a.x, b2.x, fmaf(a.y, b2.y, fmaf(a.z, b2.z, fmaf(a.w, b2.w, s2))));
        }
    }

    // ---- issue svB burst (half 1) NOW: flies under reduce0+chain0 ----
    const size_t sbase1 = ((size_t)row * NHc + n1) * (size_t)(SLOTSc * HDc);
    const v2f* stB = (const v2f*)(stack + sbase1);
    v2f svB[SLOTSc];
    #pragma unroll
    for (int k = 0; k < SLOTSc; ++k) svB[k] = stB[k * 64 + lane];
    float m1 = mask[((size_t)row * NHc + n1) * SLOTSc + cls];

    // ---- reduce + softmax-3 (half 0) ----
    #pragma unroll
    for (int o = 32; o; o >>= 1) {
        s0 += __shfl_xor(s0, o, 64);
        s1 += __shfl_xor(s1, o, 64);
        s2 += __shfl_xor(s2, o, 64);
    }
    float l0 = (s0 + b_action[3 * n0 + 0]) * scale;
    float l1 = (s1 + b_action[3 * n0 + 1]) * scale;
    float l2 = (s2 + b_action[3 * n0 + 2]) * scale;
    float lm = fmaxf(l0, fmaxf(l1, l2));
    float e0 = __expf(l0 - lm), e1 = __expf(l1 - lm), e2 = __expf(l2 - lm);
    float inv3 = 1.f / (e0 + e1 + e2);
    float a_push = e0 * inv3;
    float a_pop  = e1 * inv3;
    float a_stay = e2 * inv3;

    // ================= chain 0 (svA) =================
    {
        // distributed new_mask
        {
            int ap_prev = (grp | (cls == 0 ? 0 : cls - 1)) << 2;
            int ap_next = (grp | (cls == 15 ? 15 : cls + 1)) << 2;
            float m_prev = __int_as_float(__builtin_amdgcn_ds_bpermute(ap_prev, __float_as_int(m0)));
            float m_next = __int_as_float(__builtin_amdgcn_ds_bpermute(ap_next, __float_as_int(m0)));
            m_prev = (cls == 0)  ? 1.f : m_prev;
            m_next = (cls == 15) ? 0.f : m_next;
            m0 = a_push * m_prev + a_pop * m_next + a_stay * m0;
        }
        if (lane < SLOTSc)
            new_mask[((size_t)row * NHc + n0) * SLOTSc + lane] = m0;

        v2f kv = *(const v2f*)(hid + n0 * HDc + 2 * lane);
        v2f* nst2 = (v2f*)(new_stack + sbase0);

        // new_stack + gate partials, p folded pairwise into w8
        float w8[8];
        {
            v2f prev = kv;
            float pe = 0.f;
            #pragma unroll
            for (int k = 0; k < SLOTSc; ++k) {
                v2f cur = svA[k];
                v2f nxt;
                if (k < SLOTSc - 1) nxt = svA[k + 1];
                else { nxt.x = 0.f; nxt.y = 0.f; }
                v2f ns;
                ns.x = a_push * prev.x + a_pop * nxt.x + a_stay * cur.x;
                ns.y = a_push * prev.y + a_pop * nxt.y + a_stay * cur.y;
                svA[k] = ns;
                nst2[k * 64 + lane] = ns;
                float pk = ns.x * wg.x + ns.y * wg.y;
                if ((k & 1) == 0) pe = pk;
                else {
                    bool hi = (lane & 1);
                    float keep = hi ? pk : pe;
                    float send = hi ? pe : pk;
                    w8[k >> 1] = keep + __shfl_xor(send, 1, 64);
                }
                prev = cur;
            }
        }
        float w4[4];
        #pragma unroll
        for (int j = 0; j < 4; ++j) {
            float a = w8[2 * j], b = w8[2 * j + 1];
            bool hi = (lane & 2);
            float keep = hi ? b : a;
            float send = hi ? a : b;
            w4[j] = keep + __shfl_xor(send, 2, 64);
        }
        float w2[2];
        #pragma unroll
        for (int j = 0; j < 2; ++j) {
            float a = w4[2 * j], b = w4[2 * j + 1];
            bool hi = (lane & 4);
            float keep = hi ? b : a;
            float send = hi ? a : b;
            w2[j] = keep + __shfl_xor(send, 4, 64);
        }
        float u;
        {
            float a = w2[0], b = w2[1];
            bool hi = (lane & 8);
            float keep = hi ? b : a;
            float send = hi ? a : b;
            u = keep + __shfl_xor(send, 8, 64);
        }
        u += __shfl_xor(u, 16, 64);
        u += __shfl_xor(u, 32, 64);

        float g = u + bg + (1.f - m0) * -1000000000.0f;
        float mx = g;
        mx = fmaxf(mx, __shfl_xor(mx, 1, 64));
        mx = fmaxf(mx, __shfl_xor(mx, 2, 64));
        mx = fmaxf(mx, __shfl_xor(mx, 4, 64));
        mx = fmaxf(mx, __shfl_xor(mx, 8, 64));
        float e = __expf(g - mx);
        float ssum = e;
        ssum += __shfl_xor(ssum, 1, 64);
        ssum += __shfl_xor(ssum, 2, 64);
        ssum += __shfl_xor(ssum, 4, 64);
        ssum += __shfl_xor(ssum, 8, 64);
        float gw_d = e / ssum;

        v2f mo; mo.x = 0.f; mo.y = 0.f;
        const int grpb = grp << 2;
        #pragma unroll
        for (int k = 0; k < SLOTSc; ++k) {
            float gwk = __int_as_float(
                __builtin_amdgcn_ds_bpermute(grpb | (k << 2), __float_as_int(gw_d)));
            mo.x = fmaf(gwk, svA[k].x, mo.x);
            mo.y = fmaf(gwk, svA[k].y, mo.y);
        }
        v2f ov;
        ov.x = mo.x * rw + kv.x;
        ov.y = mo.y * rw + kv.y;
        *(v2f*)(out + (size_t)row * Hc + n0 * HDc + 2 * lane) = ov;
    }

    // ================= half 1: GEMV =================
    s0 = 0.f; s1 = 0.f; s2 = 0.f;
    {
        const float4* hl4 = (const float4*)hid;
        const float4* W0 = (const float4*)(W_action + (size_t)(3 * n1) * Hc);
        const float4* W1 = W0 + (Hc / 4);
        const float4* W2 = W1 + (Hc / 4);
        #pragma unroll 2
        for (int j = 0; j < 8; ++j) {
            float4 a  = hl4[lane + j * 64];
            float4 b0 = W0[lane + j * 64];
            float4 b1 = W1[lane + j * 64];
            float4 b2 = W2[lane + j * 64];
            s0 = fmaf(a.x, b0.x, fmaf(a.y, b0.y, fmaf(a.z, b0.z, fmaf(a.w, b0.w, s0))));
            s1 = fmaf(a.x, b1.x, fmaf(a.y, b1.y, fmaf(a.z, b1.z, fmaf(a.w, b1.w, s1))));
            s2 = fmaf(a.x, b2.x, fmaf(a.y, b2.y, fmaf(a.z, b2.z, fmaf(a.w, b2.w, s2))));
        }
    }
    #pragma unroll
    for (int o = 32; o; o >>= 1) {
        s0 += __shfl_xor(s0, o, 64);
        s1 += __shfl_xor(s1, o, 64);
        s2 += __shfl_xor(s2, o, 64);
    }
    l0 = (s0 + b_action[3 * n1 + 0]) * scale;
    l1 = (s1 + b_action[3 * n1 + 1]) * scale;
    l2 = (s2 + b_action[3 * n1 + 2]) * scale;
    lm = fmaxf(l0, fmaxf(l1, l2));
    e0 = __expf(l0 - lm); e1 = __expf(l1 - lm); e2 = __expf(l2 - lm);
    inv3 = 1.f / (e0 + e1 + e2);
    a_push = e0 * inv3;
    a_pop  = e1 * inv3;
    a_stay = e2 * inv3;

    // ================= chain 1 (svB) =================
    {
        {
            int ap_prev = (grp | (cls == 0 ? 0 : cls - 1)) << 2;
            int ap_next = (grp | (cls == 15 ? 15 : cls + 1)) << 2;
            float m_prev = __int_as_float(__builtin_amdgcn_ds_bpermute(ap_prev, __float_as_int(m1)));
            float m_next = __int_as_float(__builtin_amdgcn_ds_bpermute(ap_next, __float_as_int(m1)));
            m_prev = (cls == 0)  ? 1.f : m_prev;
            m_next = (cls == 15) ? 0.f : m_next;
            m1 = a_push * m_prev + a_pop * m_next + a_stay * m1;
        }
        if (lane < SLOTSc)
            new_mask[((size_t)row * NHc + n1) * SLOTSc + lane] = m1;

        v2f kv = *(const v2f*)(hid + n1 * HDc + 2 * lane);
        v2f* nst2 = (v2f*)(new_stack + sbase1);

        float w8[8];
        {
            v2f prev = kv;
            float pe = 0.f;
            #pragma unroll
            for (int k = 0; k < SLOTSc; ++k) {
                v2f cur = svB[k];
                v2f nxt;
                if (k < SLOTSc - 1) nxt = svB[k + 1];
                else { nxt.x = 0.f; nxt.y = 0.f; }
                v2f ns;
                ns.x = a_push * prev.x + a_pop * nxt.x + a_stay * cur.x;
                ns.y = a_push * prev.y + a_pop * nxt.y + a_stay * cur.y;
                svB[k] = ns;
                nst2[k * 64 + lane] = ns;
                float pk = ns.x * wg.x + ns.y * wg.y;
                if ((k & 1) == 0) pe = pk;
                else {
                    bool hi = (lane & 1);
                    float keep = hi ? pk : pe;
                    float send = hi ? pe : pk;
                    w8[k >> 1] = keep + __shfl_xor(send, 1, 64);
                }
                prev = cur;
            }
        }
        float w4[4];
        #pragma unroll
        for (int j = 0; j < 4; ++j) {
            float a = w8[2 * j], b = w8[2 * j + 1];
            bool hi = (lane & 2);
            float keep = hi ? b : a;
            float send = hi ? a : b;
            w4[j] = keep + __shfl_xor(send, 2, 64);
        }
        float w2[2];
        #pragma unroll
        for (int j = 0; j < 2; ++j) {
            float a = w4[2 * j], b = w4[2 * j + 1];
            bool hi = (lane & 4);
            float keep = hi ? b : a;
            float send = hi ? a : b;
            w2[j] = keep + __shfl_xor(send, 4, 64);
        }
        float u;
        {
            float a = w2[0], b = w2[1];
            bool hi = (lane & 8);
            float keep = hi ? b : a;
            float send = hi ? a : b;
            u = keep + __shfl_xor(send, 8, 64);
        }
        u += __shfl_xor(u, 16, 64);
        u += __shfl_xor(u, 32, 64);

        float g = u + bg + (1.f - m1) * -1000000000.0f;
        float mx = g;
        mx = fmaxf(mx, __shfl_xor(mx, 1, 64));
        mx = fmaxf(mx, __shfl_xor(mx, 2, 64));
        mx = fmaxf(mx, __shfl_xor(mx, 4, 64));
        mx = fmaxf(mx, __shfl_xor(mx, 8, 64));
        float e = __expf(g - mx);
        float ssum = e;
        ssum += __shfl_xor(ssum, 1, 64);
        ssum += __shfl_xor(ssum, 2, 64);
        ssum += __shfl_xor(ssum, 4, 64);
        ssum += __shfl_xor(ssum, 8, 64);
        float gw_d = e / ssum;

        v2f mo; mo.x = 0.f; mo.y = 0.f;
        const int grpb = grp << 2;
        #pragma unroll
        for (int k = 0; k < SLOTSc; ++k) {
            float gwk = __int_as_float(
                __builtin_amdgcn_ds_bpermute(grpb | (k << 2), __float_as_int(gw_d)));
            mo.x = fmaf(gwk, svB[k].x, mo.x);
            mo.y = fmaf(gwk, svB[k].y, mo.y);
        }
        v2f ov;
        ov.x = mo.x * rw + kv.x;
        ov.y = mo.y * rw + kv.y;
        *(v2f*)(out + (size_t)row * Hc + n1 * HDc + 2 * lane) = ov;
    }
}

extern "C" void kernel_launch(void* const* d_in, const int* in_sizes, int n_in,
                              void* d_out, int out_size, void* d_ws, size_t ws_size,
                              hipStream_t stream) {
    const float* hidden     = (const float*)d_in[0];
    const float* stack      = (const float*)d_in[1];
    const float* mask       = (const float*)d_in[2];
    const float* W_action   = (const float*)d_in[3];
    const float* b_action   = (const float*)d_in[4];
    const float* W_gate     = (const float*)d_in[5];
    const float* b_gate     = (const float*)d_in[6];
    const float* res_weight = (const float*)d_in[7];

    float* out       = (float*)d_out;
    float* new_stack = out + (size_t)Bc * Sc * Hc;
    float* new_mask  = new_stack + (size_t)Bc * Sc * NHc * SLOTSc * HDc;

    hipLaunchKernelGGL(stack_fused2, dim3(NROWS), dim3(512), 0, stream,
                       hidden, stack, mask, W_action, b_action,
                       W_gate, b_gate, res_weight,
                       out, new_stack, new_mask);
}

// Round 13
// 228.304 us; speedup vs baseline: 2.4789x; 1.1108x over previous
//
#include <hip/hip_runtime.h>

#define Bc 2
#define Sc 2048
#define Hc 2048
#define NHc 16
#define HDc 128
#define SLOTSc 16
#define NROWS (Bc * Sc)   // 4096

// ---------------------------------------------------------------------------
// Fused kernel (R5 == session best, 225.9 us = ~81% of achievable HBM BW).
// Block = 512 thr = 8 waves = 8 heads of one (b,s) row; grid = NROWS*2.
// Lane l owns dims 2l,2l+1 of its head (float2, 8B/lane coalesced).
//
// Per block:
//   0. issue hidden-row staging load (float4/thread) AND each wave's 16
//      stack float2 loads (HBM stream starts at t=0); ds_write; barrier.
//   1. GEMV per wave: 8 iters x (1 ds_read_b128 + 3 coalesced float4 W loads
//      + 12 fma), 18-shuffle reduce, softmax-3. W is L2-resident (384 KB).
//   2. distributed new_mask (2 bpermute), write.
//   3. new_stack in-place on sv + stores + gate partials.
//   4. merge-butterfly reduce-scatter (17 shfl) -> distributed masked
//      softmax (8 shfl, 1 exp) -> 16 bpermute broadcast -> weighted sum,
//      residual, out store.
//
// Refuted alternatives (measured): kernel split (370-400us), nontemporal
// hints (+150us), sched_barrier load reordering (+13us), W-amortization
// RPB=4 (+14us), persistent pipelined grid (spills, +340us), two-half
// pipelining (+28us). This structure is the empirical optimum.
// ---------------------------------------------------------------------------
__global__ __launch_bounds__(512, 4) void stack_fused(
    const float* __restrict__ hidden,     // [4096][2048]
    const float* __restrict__ stack,      // [4096][16][16][128]
    const float* __restrict__ mask,       // [4096][16][16]
    const float* __restrict__ W_action,   // [48][2048]
    const float* __restrict__ b_action,   // [48]
    const float* __restrict__ W_gate,     // [128]
    const float* __restrict__ b_gate,     // [1]
    const float* __restrict__ res_weight, // [1]
    float* __restrict__ out,              // [4096][2048]
    float* __restrict__ new_stack,        // [4096][16][16][128]
    float* __restrict__ new_mask)         // [4096][16][16]
{
    __shared__ float hid[Hc]; // 8 KB

    const int bs   = blockIdx.x >> 1;
    const int half = blockIdx.x & 1;
    const int tid  = threadIdx.x;
    const int lane = tid & 63;
    const int wave = tid >> 6;
    const int n    = half * 8 + wave;

    // ---- phase 0: staging load + stack stream issue ----
    const float4* hrow4 = (const float4*)(hidden + (size_t)bs * Hc);
    float4 hstage = hrow4[tid]; // 512 thr x 16B = 8 KB

    const size_t sbase = ((size_t)bs * NHc + n) * (size_t)(SLOTSc * HDc);
    const float2* st2  = (const float2*)(stack + sbase);
    float2 sv[SLOTSc];
    #pragma unroll
    for (int k = 0; k < SLOTSc; ++k) sv[k] = st2[k * 64 + lane];

    const int cls = lane & 15;
    const int grp = lane & 48;
    float m_d = mask[((size_t)bs * NHc + n) * SLOTSc + cls];
    float2 wg = *(const float2*)(W_gate + 2 * lane);

    ((float4*)hid)[tid] = hstage;
    __syncthreads();

    // ---- phase 1: GEMV (vectorized) ----
    float s0 = 0.f, s1 = 0.f, s2 = 0.f;
    {
        const float4* hl = (const float4*)hid;
        const float4* W0 = (const float4*)(W_action + (size_t)(3 * n) * Hc);
        const float4* W1 = W0 + (Hc / 4);
        const float4* W2 = W1 + (Hc / 4);
        #pragma unroll 2
        for (int j = 0; j < 8; ++j) {
            float4 a  = hl[lane + j * 64];
            float4 b0 = W0[lane + j * 64];
            float4 b1 = W1[lane + j * 64];
            float4 b2 = W2[lane + j * 64];
            s0 = fmaf(a.x, b0.x, fmaf(a.y, b0.y, fmaf(a.z, b0.z, fmaf(a.w, b0.w, s0))));
            s1 = fmaf(a.x, b1.x, fmaf(a.y, b1.y, fmaf(a.z, b1.z, fmaf(a.w, b1.w, s1))));
            s2 = fmaf(a.x, b2.x, fmaf(a.y, b2.y, fmaf(a.z, b2.z, fmaf(a.w, b2.w, s2))));
        }
    }
    #pragma unroll
    for (int o = 32; o; o >>= 1) {
        s0 += __shfl_xor(s0, o, 64);
        s1 += __shfl_xor(s1, o, 64);
        s2 += __shfl_xor(s2, o, 64);
    }
    const float scale = 0.08838834764831845f; // 1/sqrt(128)
    float l0 = (s0 + b_action[3 * n + 0]) * scale;
    float l1 = (s1 + b_action[3 * n + 1]) * scale;
    float l2 = (s2 + b_action[3 * n + 2]) * scale;
    float lm = fmaxf(l0, fmaxf(l1, l2));
    float e0 = __expf(l0 - lm), e1 = __expf(l1 - lm), e2 = __expf(l2 - lm);
    float inv3 = 1.f / (e0 + e1 + e2);
    const float a_push = e0 * inv3;
    const float a_pop  = e1 * inv3;
    const float a_stay = e2 * inv3;

    float2 kv = *(const float2*)(hid + n * HDc + 2 * lane);

    // ---- phase 2: distributed new_mask ----
    {
        int ap_prev = (grp | (cls == 0 ? 0 : cls - 1)) << 2;
        int ap_next = (grp | (cls == 15 ? 15 : cls + 1)) << 2;
        float m_prev = __int_as_float(__builtin_amdgcn_ds_bpermute(ap_prev, __float_as_int(m_d)));
        float m_next = __int_as_float(__builtin_amdgcn_ds_bpermute(ap_next, __float_as_int(m_d)));
        m_prev = (cls == 0)  ? 1.f : m_prev;
        m_next = (cls == 15) ? 0.f : m_next;
        m_d = a_push * m_prev + a_pop * m_next + a_stay * m_d;  // now new_mask
    }
    if (lane < SLOTSc)
        new_mask[((size_t)bs * NHc + n) * SLOTSc + lane] = m_d;

    // ---- phase 3: new_stack (in-place on sv) + stores + gate partials ----
    const float bg = b_gate[0];
    const float rw = res_weight[0];
    float2* nst2 = (float2*)(new_stack + sbase);
    float p[SLOTSc];
    {
        float2 prev = kv;
        #pragma unroll
        for (int k = 0; k < SLOTSc; ++k) {
            float2 cur = sv[k];
            float2 nxt;
            if (k < SLOTSc - 1) nxt = sv[k + 1];
            else { nxt.x = 0.f; nxt.y = 0.f; }
            float2 ns;
            ns.x = a_push * prev.x + a_pop * nxt.x + a_stay * cur.x;
            ns.y = a_push * prev.y + a_pop * nxt.y + a_stay * cur.y;
            sv[k] = ns;
            nst2[k * 64 + lane] = ns;
            p[k] = ns.x * wg.x + ns.y * wg.y;
            prev = cur;
        }
    }

    // ---- phase 4a: merge-butterfly reduce-scatter (slot k -> lane&15==k) ----
    float w8[8];
    #pragma unroll
    for (int j = 0; j < 8; ++j) {
        float a = p[2 * j], b = p[2 * j + 1];
        bool hi = (lane & 1);
        float keep = hi ? b : a;
        float send = hi ? a : b;
        w8[j] = keep + __shfl_xor(send, 1, 64);
    }
    float w4[4];
    #pragma unroll
    for (int j = 0; j < 4; ++j) {
        float a = w8[2 * j], b = w8[2 * j + 1];
        bool hi = (lane & 2);
        float keep = hi ? b : a;
        float send = hi ? a : b;
        w4[j] = keep + __shfl_xor(send, 2, 64);
    }
    float w2[2];
    #pragma unroll
    for (int j = 0; j < 2; ++j) {
        float a = w4[2 * j], b = w4[2 * j + 1];
        bool hi = (lane & 4);
        float keep = hi ? b : a;
        float send = hi ? a : b;
        w2[j] = keep + __shfl_xor(send, 4, 64);
    }
    float u;
    {
        float a = w2[0], b = w2[1];
        bool hi = (lane & 8);
        float keep = hi ? b : a;
        float send = hi ? a : b;
        u = keep + __shfl_xor(send, 8, 64);
    }
    u += __shfl_xor(u, 16, 64);
    u += __shfl_xor(u, 32, 64);
    // u = dot(new_stack[l&15], W_gate) over all 128 dims

    // ---- phase 4b: distributed masked softmax over 16 slots ----
    float g = u + bg + (1.f - m_d) * -1000000000.0f;
    float mx = g;
    mx = fmaxf(mx, __shfl_xor(mx, 1, 64));
    mx = fmaxf(mx, __shfl_xor(mx, 2, 64));
    mx = fmaxf(mx, __shfl_xor(mx, 4, 64));
    mx = fmaxf(mx, __shfl_xor(mx, 8, 64));
    float e = __expf(g - mx);
    float ssum = e;
    ssum += __shfl_xor(ssum, 1, 64);
    ssum += __shfl_xor(ssum, 2, 64);
    ssum += __shfl_xor(ssum, 4, 64);
    ssum += __shfl_xor(ssum, 8, 64);
    float gw_d = e / ssum;   // gate weight for slot l&15

    // ---- phase 4c: broadcast gate weights; weighted sum + residual ----
    float2 mo; mo.x = 0.f; mo.y = 0.f;
    const int grpb = grp << 2;
    #pragma unroll
    for (int k = 0; k < SLOTSc; ++k) {
        float gwk = __int_as_float(
            __builtin_amdgcn_ds_bpermute(grpb | (k << 2), __float_as_int(gw_d)));
        mo.x = fmaf(gwk, sv[k].x, mo.x);
        mo.y = fmaf(gwk, sv[k].y, mo.y);
    }
    float2 ov;
    ov.x = mo.x * rw + kv.x;
    ov.y = mo.y * rw + kv.y;
    *(float2*)(out + (size_t)bs * Hc + n * HDc + 2 * lane) = ov;
}

extern "C" void kernel_launch(void* const* d_in, const int* in_sizes, int n_in,
                              void* d_out, int out_size, void* d_ws, size_t ws_size,
                              hipStream_t stream) {
    const float* hidden     = (const float*)d_in[0];
    const float* stack      = (const float*)d_in[1];
    const float* mask       = (const float*)d_in[2];
    const float* W_action   = (const float*)d_in[3];
    const float* b_action   = (const float*)d_in[4];
    const float* W_gate     = (const float*)d_in[5];
    const float* b_gate     = (const float*)d_in[6];
    const float* res_weight = (const float*)d_in[7];

    float* out       = (float*)d_out;
    float* new_stack = out + (size_t)Bc * Sc * Hc;
    float* new_mask  = new_stack + (size_t)Bc * Sc * NHc * SLOTSc * HDc;

    hipLaunchKernelGGL(stack_fused, dim3(NROWS * 2), dim3(512), 0, stream,
                       hidden, stack, mask, W_action, b_action,
                       W_gate, b_gate, res_weight,
                       out, new_stack, new_mask);
}